// Round 1
// baseline (1877.515 us; speedup 1.0000x reference)
//
#include <hip/hip_runtime.h>

typedef float v2f __attribute__((ext_vector_type(2)));
typedef float v4f __attribute__((ext_vector_type(4)));

#define TILE_S 64      // samples per block
#define KC 70          // K-chunk: 2 conv channels x 35 spatial
#define SPATIAL 35
#define K1 350
#define N1 256
#define NCHUNK 5

static __device__ __forceinline__ v2f splat2(float x) {
    v2f r; r.x = x; r.y = x; return r;
}

__global__ __launch_bounds__(256, 3)
void fused_actor_critic(const float* __restrict__ state,
                        const float* __restrict__ wa, const float* __restrict__ ba,
                        const float* __restrict__ w1, const float* __restrict__ b1,
                        const float* __restrict__ w2, const float* __restrict__ b2,
                        const float* __restrict__ wc, const float* __restrict__ bc,
                        const float* __restrict__ wlc, const float* __restrict__ blc,
                        float* __restrict__ out, int batch)
{
    // state transposed [ij][s], +1 pad to break 64-stride bank aliasing
    __shared__ float s_state[SPATIAL][TILE_S + 1];   // ~9.1 KB
    // ha chunk [k][s]; row = 256B (16B-aligned for b128 reads, broadcast pattern)
    __shared__ float s_ha[KC][TILE_S];               // ~17.9 KB

    const int t  = threadIdx.x;
    const int ng = t & 31;      // neuron group: all 32 in one 32-lane half
    const int sg = t >> 5;      // sample group 0..7
    const int n0 = ng * 8;
    const int s_base = blockIdx.x * TILE_S;

    // ---- stage state tile (coalesced global read, transposed LDS write) ----
    for (int i = t; i < TILE_S * SPATIAL; i += 256) {
        int s  = i / SPATIAL;
        int ij = i - s * SPATIAL;
        s_state[ij][s] = state[(size_t)(s_base + s) * SPATIAL + ij];
    }
    __syncthreads();

    // ---- FC1 accumulators: 8 samples (4 x float2) x 8 neurons ----
    v2f acc[4][8];
    #pragma unroll
    for (int p = 0; p < 4; ++p)
        #pragma unroll
        for (int j = 0; j < 8; ++j)
            acc[p][j] = splat2(0.f);

    const float* wbase = w1 + (size_t)n0 * K1;

    for (int ch = 0; ch < NCHUNK; ++ch) {
        // ---- recompute ha chunk (conv 1x1 + relu) into LDS ----
        const int c0 = 2 * ch;
        const float wa0 = wa[c0], wa1 = wa[c0 + 1];
        const float ba0 = ba[c0], ba1 = ba[c0 + 1];
        #pragma unroll
        for (int rep = 0; rep < 18; ++rep) {      // ceil(70*64/256)
            int i = t + rep * 256;
            if (i < KC * TILE_S) {
                int k = i >> 6;
                int s = i & 63;
                bool hi = (k >= SPATIAL);
                int ij = hi ? (k - SPATIAL) : k;
                float x = s_state[ij][s];
                float v = hi ? (wa1 * x + ba1) : (wa0 * x + ba0);
                s_ha[k][s] = fmaxf(v, 0.f);
            }
        }
        __syncthreads();

        // ---- GEMM over this K-chunk: W1 streamed from L2 (row-major, k-contig) ----
        const float* wp = wbase + ch * KC;
        for (int k = 0; k < KC; k += 2) {
            // A: 8 samples for k and k+1 (32-lane broadcast LDS reads)
            v4f x0 = *(const v4f*)&s_ha[k][sg * 8];
            v4f x1 = *(const v4f*)&s_ha[k][sg * 8 + 4];
            v4f y0 = *(const v4f*)&s_ha[k + 1][sg * 8];
            v4f y1 = *(const v4f*)&s_ha[k + 1][sg * 8 + 4];
            v2f aL[4] = { {x0.x,x0.y},{x0.z,x0.w},{x1.x,x1.y},{x1.z,x1.w} };
            v2f aR[4] = { {y0.x,y0.y},{y0.z,y0.w},{y1.x,y1.y},{y1.z,y1.w} };
            #pragma unroll
            for (int j = 0; j < 8; ++j) {
                v2f wv = *(const v2f*)&wp[j * K1 + k];   // w1[n0+j][k], [k+1]
                v2f w0 = splat2(wv.x);
                v2f w1s = splat2(wv.y);
                #pragma unroll
                for (int p = 0; p < 4; ++p) {
                    acc[p][j] = __builtin_elementwise_fma(aL[p], w0,  acc[p][j]);
                    acc[p][j] = __builtin_elementwise_fma(aR[p], w1s, acc[p][j]);
                }
            }
        }
        __syncthreads();
    }

    // ---- bias + relu -> h1 (in registers) ----
    {
        v4f bv0 = *(const v4f*)&b1[n0];
        v4f bv1 = *(const v4f*)&b1[n0 + 4];
        float bb[8] = {bv0.x,bv0.y,bv0.z,bv0.w,bv1.x,bv1.y,bv1.z,bv1.w};
        #pragma unroll
        for (int j = 0; j < 8; ++j)
            #pragma unroll
            for (int p = 0; p < 4; ++p) {
                acc[p][j].x = fmaxf(acc[p][j].x + bb[j], 0.f);
                acc[p][j].y = fmaxf(acc[p][j].y + bb[j], 0.f);
            }
    }

    // ---- FC2: per-l partial over this thread's 8 neurons, shfl-reduce 32 lanes ----
    #pragma unroll
    for (int l = 0; l < 5; ++l) {
        v4f w2v0 = *(const v4f*)&w2[l * N1 + n0];
        v4f w2v1 = *(const v4f*)&w2[l * N1 + n0 + 4];
        float wj[8] = {w2v0.x,w2v0.y,w2v0.z,w2v0.w,w2v1.x,w2v1.y,w2v1.z,w2v1.w};
        v2f p2[4] = {splat2(0.f), splat2(0.f), splat2(0.f), splat2(0.f)};
        #pragma unroll
        for (int j = 0; j < 8; ++j) {
            v2f ws = splat2(wj[j]);
            #pragma unroll
            for (int p = 0; p < 4; ++p)
                p2[p] = __builtin_elementwise_fma(acc[p][j], ws, p2[p]);
        }
        float pv[8] = {p2[0].x,p2[0].y,p2[1].x,p2[1].y,p2[2].x,p2[2].y,p2[3].x,p2[3].y};
        #pragma unroll
        for (int off = 1; off < 32; off <<= 1)
            #pragma unroll
            for (int i = 0; i < 8; ++i)
                pv[i] += __shfl_xor(pv[i], off);
        if (ng == 0) {
            float bl = b2[l];
            #pragma unroll
            for (int i = 0; i < 8; ++i)
                out[(size_t)(s_base + sg * 8 + i) * 5 + l] = pv[i] + bl;
        }
    }

    // ---- critic: one lane per sample (wave 0), state still in LDS ----
    if (t < TILE_S) {
        float v = blc[0];
        #pragma unroll
        for (int ij = 0; ij < SPATIAL; ++ij) {
            float s = s_state[ij][t];
            #pragma unroll
            for (int c = 0; c < 3; ++c) {
                float h = fmaxf(wc[c] * s + bc[c], 0.f);
                v += wlc[c * SPATIAL + ij] * h;
            }
        }
        out[(size_t)5 * batch + s_base + t] = v;
    }
}

extern "C" void kernel_launch(void* const* d_in, const int* in_sizes, int n_in,
                              void* d_out, int out_size, void* d_ws, size_t ws_size,
                              hipStream_t stream) {
    const float* state = (const float*)d_in[0];
    const float* wa    = (const float*)d_in[1];
    const float* ba    = (const float*)d_in[2];
    const float* w1    = (const float*)d_in[3];
    const float* b1    = (const float*)d_in[4];
    const float* w2    = (const float*)d_in[5];
    const float* b2    = (const float*)d_in[6];
    const float* wc    = (const float*)d_in[7];
    const float* bc    = (const float*)d_in[8];
    const float* wlc   = (const float*)d_in[9];
    const float* blc   = (const float*)d_in[10];
    float* out = (float*)d_out;

    int B = in_sizes[0] / SPATIAL;          // 262144
    int grid = B / TILE_S;                  // 4096 blocks (B divisible by 64)
    hipLaunchKernelGGL(fused_actor_critic, dim3(grid), dim3(256), 0, stream,
                       state, wa, ba, w1, b1, w2, b2, wc, bc, wlc, blc, out, B);
}

// Round 2
// 291.045 us; speedup vs baseline: 6.4509x; 6.4509x over previous
//
#include <hip/hip_runtime.h>
#include <hip/hip_bf16.h>

typedef short bf16x8 __attribute__((ext_vector_type(8)));   // 8 bf16 = 4 VGPRs
typedef float f32x4  __attribute__((ext_vector_type(4)));

#define SPATIAL 35
#define K1 350
#define KPAD 352          // 11 * 32
#define N1 256
#define TILE_M 64
#define AROW 360          // LDS A row in bf16 elems (720 B): <=2-way bank alias (free)
#define NCHUNK 11

// ---- pre-kernel: w1 fp32 [256][350] -> bf16 [256][352] (RNE, zero-padded) ----
__global__ void convert_w1(const float* __restrict__ w1, unsigned short* __restrict__ w1b) {
    int i = blockIdx.x * 256 + threadIdx.x;          // i < 256*352
    int n = i / KPAD;
    int k = i - n * KPAD;
    float v = (k < K1) ? w1[n * K1 + k] : 0.f;
    __hip_bfloat16 b = __float2bfloat16(v);
    w1b[i] = __builtin_bit_cast(unsigned short, b);
}

__global__ __launch_bounds__(256, 3)
void fused_actor_critic_mfma(const float* __restrict__ state,
                             const float* __restrict__ wa, const float* __restrict__ ba,
                             const unsigned short* __restrict__ w1b, const float* __restrict__ b1,
                             const float* __restrict__ w2, const float* __restrict__ b2,
                             const float* __restrict__ wc, const float* __restrict__ bc,
                             const float* __restrict__ wlc, const float* __restrict__ blc,
                             float* __restrict__ out, int batch)
{
    __shared__ __align__(16) unsigned short s_A[TILE_M * AROW];   // 46080 B

    const int t      = threadIdx.x;
    const int lane   = t & 63;
    const int wave   = t >> 6;
    const int s_base = blockIdx.x * TILE_M;

    // ---- stage A = relu(conv1x1(state)) as bf16, K padded to 352 ----
    {
        const int s    = t & 63;          // sample within tile
        const int q4   = t >> 6;          // 4 threads per sample, 88 k each
        const int k0   = q4 * 88;
        const int kend = (k0 + 88 < K1) ? (k0 + 88) : K1;
        int c  = k0 / 35;                 // wave-uniform
        int ij = k0 - c * 35;
        float wac = wa[c], bac = ba[c];
        const float* srow = state + (size_t)(s_base + s) * SPATIAL;
        unsigned short* arow = s_A + s * AROW;
        int k = k0;
        #pragma unroll 4
        for (int r2 = 0; r2 < 44; ++r2) {
            float h0 = 0.f, h1v = 0.f;
            if (k < kend) {
                h0 = fmaxf(fmaf(srow[ij], wac, bac), 0.f);
                if (++ij == 35) { ij = 0; if (++c < 10) { wac = wa[c]; bac = ba[c]; } }
            }
            if (k + 1 < kend) {
                h1v = fmaxf(fmaf(srow[ij], wac, bac), 0.f);
                if (++ij == 35) { ij = 0; if (++c < 10) { wac = wa[c]; bac = ba[c]; } }
            }
            unsigned short u0 = __builtin_bit_cast(unsigned short, __float2bfloat16(h0));
            unsigned short u1 = __builtin_bit_cast(unsigned short, __float2bfloat16(h1v));
            unsigned int pk = (unsigned int)u0 | ((unsigned int)u1 << 16);
            *reinterpret_cast<unsigned int*>(arow + k) = pk;
            k += 2;
        }
    }
    __syncthreads();

    // ---- MFMA K-loop: wave handles M=64 x N=64 (n0w..n0w+63) ----
    const int n0w = wave * 64;
    const int lq  = lane >> 4;     // quad 0..3
    const int lm  = lane & 15;

    f32x4 acc[4][4];               // [mt][nt]
    #pragma unroll
    for (int mt = 0; mt < 4; ++mt)
        #pragma unroll
        for (int nt = 0; nt < 4; ++nt)
            acc[mt][nt] = (f32x4){0.f, 0.f, 0.f, 0.f};

    const unsigned short* wbase[4];
    #pragma unroll
    for (int nt = 0; nt < 4; ++nt)
        wbase[nt] = w1b + (size_t)(n0w + 16 * nt + lm) * KPAD + lq * 8;

    #pragma unroll 2
    for (int ch = 0; ch < NCHUNK; ++ch) {
        const int kc = ch * 32;
        bf16x8 bfrag[4], afrag[4];
        #pragma unroll
        for (int nt = 0; nt < 4; ++nt)
            bfrag[nt] = *reinterpret_cast<const bf16x8*>(wbase[nt] + kc);
        #pragma unroll
        for (int mt = 0; mt < 4; ++mt)
            afrag[mt] = *reinterpret_cast<const bf16x8*>(s_A + (16 * mt + lm) * AROW + kc + lq * 8);
        #pragma unroll
        for (int mt = 0; mt < 4; ++mt)
            #pragma unroll
            for (int nt = 0; nt < 4; ++nt)
                acc[mt][nt] = __builtin_amdgcn_mfma_f32_16x16x32_bf16(
                    afrag[mt], bfrag[nt], acc[mt][nt], 0, 0, 0);
    }

    __syncthreads();               // all A reads done; reuse s_A as fp32 scratch
    float* part = reinterpret_cast<float*>(s_A);    // [wave][s][l] = w*320 + s*5 + l

    // ---- bias + relu (h1 in acc, fp32) ----
    float bn[4];
    #pragma unroll
    for (int nt = 0; nt < 4; ++nt) bn[nt] = b1[n0w + 16 * nt + lm];
    #pragma unroll
    for (int mt = 0; mt < 4; ++mt)
        #pragma unroll
        for (int nt = 0; nt < 4; ++nt)
            #pragma unroll
            for (int r = 0; r < 4; ++r)
                acc[mt][nt][r] = fmaxf(acc[mt][nt][r] + bn[nt], 0.f);

    // ---- FC2 partials over this wave's 64 neurons ----
    #pragma unroll
    for (int l = 0; l < 5; ++l) {
        float w2v[4];
        #pragma unroll
        for (int nt = 0; nt < 4; ++nt) w2v[nt] = w2[l * N1 + n0w + 16 * nt + lm];
        #pragma unroll
        for (int mt = 0; mt < 4; ++mt) {
            #pragma unroll
            for (int r = 0; r < 4; ++r) {
                float p = acc[mt][0][r] * w2v[0];
                p = fmaf(acc[mt][1][r], w2v[1], p);
                p = fmaf(acc[mt][2][r], w2v[2], p);
                p = fmaf(acc[mt][3][r], w2v[3], p);
                p += __shfl_xor(p, 1);
                p += __shfl_xor(p, 2);
                p += __shfl_xor(p, 4);
                p += __shfl_xor(p, 8);
                if (lm == 0) {
                    int s = 16 * mt + 4 * lq + r;
                    part[wave * 320 + s * 5 + l] = p;
                }
            }
        }
    }
    __syncthreads();

    // ---- final FC2 combine (t<64) and critic (64<=t<128) ----
    if (t < 64) {
        const int gs = s_base + t;
        #pragma unroll
        for (int l = 0; l < 5; ++l) {
            float v = part[t * 5 + l] + part[320 + t * 5 + l]
                    + part[640 + t * 5 + l] + part[960 + t * 5 + l] + b2[l];
            out[(size_t)gs * 5 + l] = v;
        }
    } else if (t < 128) {
        const int s  = t - 64;
        const int gs = s_base + s;
        const float* srow = state + (size_t)gs * SPATIAL;
        float v = blc[0];
        #pragma unroll
        for (int ij = 0; ij < SPATIAL; ++ij) {
            float x = srow[ij];
            #pragma unroll
            for (int c = 0; c < 3; ++c)
                v = fmaf(wlc[c * SPATIAL + ij], fmaxf(fmaf(x, wc[c], bc[c]), 0.f), v);
        }
        out[(size_t)5 * batch + gs] = v;
    }
}

extern "C" void kernel_launch(void* const* d_in, const int* in_sizes, int n_in,
                              void* d_out, int out_size, void* d_ws, size_t ws_size,
                              hipStream_t stream) {
    const float* state = (const float*)d_in[0];
    const float* wa    = (const float*)d_in[1];
    const float* ba    = (const float*)d_in[2];
    const float* w1    = (const float*)d_in[3];
    const float* b1    = (const float*)d_in[4];
    const float* w2    = (const float*)d_in[5];
    const float* b2    = (const float*)d_in[6];
    const float* wc    = (const float*)d_in[7];
    const float* bc    = (const float*)d_in[8];
    const float* wlc   = (const float*)d_in[9];
    const float* blc   = (const float*)d_in[10];
    float* out = (float*)d_out;
    unsigned short* w1b = (unsigned short*)d_ws;     // 256*352*2 = 180224 B

    int B = in_sizes[0] / SPATIAL;                   // 262144
    hipLaunchKernelGGL(convert_w1, dim3((N1 * KPAD) / 256), dim3(256), 0, stream, w1, w1b);
    hipLaunchKernelGGL(fused_actor_critic_mfma, dim3(B / TILE_M), dim3(256), 0, stream,
                       state, wa, ba, w1b, b1, w2, b2, wc, bc, wlc, blc, out, B);
}

// Round 3
// 219.567 us; speedup vs baseline: 8.5510x; 1.3255x over previous
//
#include <hip/hip_runtime.h>
#include <hip/hip_bf16.h>

typedef short bf16x8 __attribute__((ext_vector_type(8)));   // 8 bf16 = 4 VGPRs
typedef float f32x4  __attribute__((ext_vector_type(4)));
typedef unsigned int u32x4 __attribute__((ext_vector_type(4)));

#define SPATIAL 35
#define K1 350
#define KPAD 352          // 11 chunks of 32
#define N1 256
#define TILE_M 64
#define NCHUNK 11
#define AROWE 352         // s_A row elems (704 B); granule = 8 bf16 = 16 B, 44/row

// ---- pre-kernel: w1 [256][350] f32 -> chunk-major bf16 w1t[ch][n][32] ----
__global__ void convert_w1(const float* __restrict__ w1, unsigned short* __restrict__ w1t) {
    int i  = blockIdx.x * 256 + threadIdx.x;    // < 256*352 = 90112
    int kk = i & 31;
    int n  = (i >> 5) & 255;
    int ch = i >> 13;
    int k  = ch * 32 + kk;
    float v = (k < K1) ? w1[n * K1 + k] : 0.f;
    w1t[i] = __builtin_bit_cast(unsigned short, __float2bfloat16(v));
}

__global__ __launch_bounds__(256, 3)
void fused_actor_critic_mfma2(const float* __restrict__ state,
                              const float* __restrict__ wa, const float* __restrict__ ba,
                              const unsigned short* __restrict__ w1t, const float* __restrict__ b1,
                              const float* __restrict__ w2, const float* __restrict__ b2,
                              const float* __restrict__ wc, const float* __restrict__ bc,
                              const float* __restrict__ wlc, const float* __restrict__ blc,
                              float* __restrict__ out, int batch)
{
    __shared__ __align__(16) unsigned short s_A[TILE_M * AROWE];   // 45056 B, swizzled
    __shared__ __align__(16) float s_misc[2304];                   // 9216 B: state, later partials

    const int t    = threadIdx.x;
    const int lane = t & 63;
    const int wave = t >> 6;
    const int lm   = lane & 15;
    const int lq   = lane >> 4;
    const int s_base = blockIdx.x * TILE_M;
    const int n0w  = wave * 64;

    // ---- W prefetch: chunks 0,1 issued before staging (contiguous 1KB/instr) ----
    bf16x8 wf[2][4], af[2][4];
    const unsigned short* wrow = w1t + (size_t)(n0w + lm) * 32 + lq * 8;
    #pragma unroll
    for (int nt = 0; nt < 4; ++nt) wf[0][nt] = *(const bf16x8*)(wrow + nt * 512);
    #pragma unroll
    for (int nt = 0; nt < 4; ++nt) wf[1][nt] = *(const bf16x8*)(wrow + 8192 + nt * 512);

    // ---- stage 1: state tile -> LDS, coalesced ----
    {
        const float* src = state + (size_t)s_base * SPATIAL;
        #pragma unroll
        for (int r = 0; r < 9; ++r) {
            int idx = t + r * 256;
            if (idx < TILE_M * SPATIAL) s_misc[idx] = src[idx];
        }
    }
    __syncthreads();

    // ---- stage 2: conv1x1+relu -> bf16 A tile (swizzled granules, b128 writes) ----
    {
        const int s = lane;                      // sample; wave = k-quarter
        const float* srow = s_misc + s * SPATIAL;   // stride 35 dwords (odd) = conflict-free
        int k  = wave * 88;
        int c  = k / SPATIAL;
        int ij = k - c * SPATIAL;
        float wac = wa[c], bac = ba[c];
        #pragma unroll
        for (int r = 0; r < 11; ++r) {
            unsigned int dw[4];
            #pragma unroll
            for (int pp = 0; pp < 4; ++pp) {
                float h0 = 0.f, h1f = 0.f;
                if (k < K1) {
                    h0 = fmaxf(fmaf(srow[ij], wac, bac), 0.f);
                    if (++ij == SPATIAL) { ij = 0; if (++c < 10) { wac = wa[c]; bac = ba[c]; } }
                }
                ++k;
                if (k < K1) {
                    h1f = fmaxf(fmaf(srow[ij], wac, bac), 0.f);
                    if (++ij == SPATIAL) { ij = 0; if (++c < 10) { wac = wa[c]; bac = ba[c]; } }
                }
                ++k;
                unsigned int u0 = (unsigned int)__builtin_bit_cast(unsigned short, __float2bfloat16(h0));
                unsigned int u1 = (unsigned int)__builtin_bit_cast(unsigned short, __float2bfloat16(h1f));
                dw[pp] = u0 | (u1 << 16);
            }
            int g  = wave * 11 + r;
            int gs = (g & ~3) | ((g & 3) ^ (s & 3));   // XOR swizzle on 16B granules
            ((u32x4*)s_A)[s * 44 + gs] = (u32x4){dw[0], dw[1], dw[2], dw[3]};
        }
    }
    __syncthreads();

    // ---- K loop: h1^T = W1 * ha^T  (operands swapped: D[n][m]) ----
    const unsigned short* afbase[4];
    #pragma unroll
    for (int mt = 0; mt < 4; ++mt)
        afbase[mt] = s_A + (16 * mt + lm) * AROWE + (lq ^ (lm & 3)) * 8;

    f32x4 acc[4][4];                 // [nt][mt]
    #pragma unroll
    for (int nt = 0; nt < 4; ++nt)
        #pragma unroll
        for (int mt = 0; mt < 4; ++mt)
            acc[nt][mt] = (f32x4){0.f, 0.f, 0.f, 0.f};

    #pragma unroll
    for (int mt = 0; mt < 4; ++mt) af[0][mt] = *(const bf16x8*)(afbase[mt]);

    #pragma unroll
    for (int ch = 0; ch < NCHUNK; ++ch) {
        const int cur = ch & 1;
        if (ch + 1 < NCHUNK) {
            #pragma unroll
            for (int mt = 0; mt < 4; ++mt)
                af[cur ^ 1][mt] = *(const bf16x8*)(afbase[mt] + (ch + 1) * 32);
        }
        #pragma unroll
        for (int nt = 0; nt < 4; ++nt)
            #pragma unroll
            for (int mt = 0; mt < 4; ++mt)
                acc[nt][mt] = __builtin_amdgcn_mfma_f32_16x16x32_bf16(
                    wf[cur][nt], af[cur][mt], acc[nt][mt], 0, 0, 0);
        if (ch + 2 < NCHUNK) {
            #pragma unroll
            for (int nt = 0; nt < 4; ++nt)
                wf[cur][nt] = *(const bf16x8*)(wrow + (size_t)(ch + 2) * 8192 + nt * 512);
        }
    }

    // ---- critic partial while s_misc still holds raw state ----
    float cv = 0.f;
    {
        const int ij0 = wave * 9;
        const int nij = (wave < 3) ? 9 : 8;
        const float* srow = s_misc + lane * SPATIAL;
        #pragma unroll
        for (int u = 0; u < 9; ++u) {
            if (u < nij) {
                int ij = ij0 + u;
                float x = srow[ij];
                #pragma unroll
                for (int c = 0; c < 3; ++c)
                    cv = fmaf(wlc[c * SPATIAL + ij], fmaxf(fmaf(x, wc[c], bc[c]), 0.f), cv);
            }
        }
    }
    __syncthreads();                 // all reads of s_misc (state) and s_A done

    // ---- bias + relu (h1^T rows n = n0w + 16nt + 4lq + r) ----
    {
        #pragma unroll
        for (int nt = 0; nt < 4; ++nt) {
            f32x4 bv = *(const f32x4*)&b1[n0w + 16 * nt + 4 * lq];
            #pragma unroll
            for (int mt = 0; mt < 4; ++mt)
                #pragma unroll
                for (int r = 0; r < 4; ++r)
                    acc[nt][mt][r] = fmaxf(acc[nt][mt][r] + bv[r], 0.f);
        }
    }

    // ---- FC2: reduce over lq only (2 shfl steps), write partials ----
    float* part = s_misc;            // [wave][m][l] : wave*320 + m*5 + l
    float* crit = s_misc + 1280;     // [wave][s]    : wave*64 + s
    #pragma unroll
    for (int l = 0; l < 5; ++l) {
        f32x4 wv[4];
        #pragma unroll
        for (int nt = 0; nt < 4; ++nt)
            wv[nt] = *(const f32x4*)&w2[l * N1 + n0w + 16 * nt + 4 * lq];
        #pragma unroll
        for (int mt = 0; mt < 4; ++mt) {
            float p = 0.f;
            #pragma unroll
            for (int nt = 0; nt < 4; ++nt)
                #pragma unroll
                for (int r = 0; r < 4; ++r)
                    p = fmaf(acc[nt][mt][r], wv[nt][r], p);
            p += __shfl_xor(p, 16);
            p += __shfl_xor(p, 32);
            bool mine = (l < 4) ? (lq == l) : (lq == 0);
            if (mine) part[wave * 320 + (16 * mt + lm) * 5 + l] = p;
        }
    }
    crit[wave * 64 + lane] = cv;
    __syncthreads();

    // ---- final combine ----
    if (t < TILE_M) {
        const int gs = s_base + t;
        #pragma unroll
        for (int l = 0; l < 5; ++l) {
            float v = part[t * 5 + l] + part[320 + t * 5 + l]
                    + part[640 + t * 5 + l] + part[960 + t * 5 + l] + b2[l];
            out[(size_t)gs * 5 + l] = v;
        }
    } else if (t < 128) {
        const int s = t - 64;
        float v = crit[s] + crit[64 + s] + crit[128 + s] + crit[192 + s] + blc[0];
        out[(size_t)5 * batch + s_base + s] = v;
    }
}

extern "C" void kernel_launch(void* const* d_in, const int* in_sizes, int n_in,
                              void* d_out, int out_size, void* d_ws, size_t ws_size,
                              hipStream_t stream) {
    const float* state = (const float*)d_in[0];
    const float* wa    = (const float*)d_in[1];
    const float* ba    = (const float*)d_in[2];
    const float* w1    = (const float*)d_in[3];
    const float* b1    = (const float*)d_in[4];
    const float* w2    = (const float*)d_in[5];
    const float* b2    = (const float*)d_in[6];
    const float* wc    = (const float*)d_in[7];
    const float* bc    = (const float*)d_in[8];
    const float* wlc   = (const float*)d_in[9];
    const float* blc   = (const float*)d_in[10];
    float* out = (float*)d_out;
    unsigned short* w1t = (unsigned short*)d_ws;     // 256*352*2 = 180224 B

    int B = in_sizes[0] / SPATIAL;                   // 262144
    hipLaunchKernelGGL(convert_w1, dim3((N1 * KPAD) / 256), dim3(256), 0, stream, w1, w1t);
    hipLaunchKernelGGL(fused_actor_critic_mfma2, dim3(B / TILE_M), dim3(256), 0, stream,
                       state, wa, ba, w1t, b1, w2, b2, wc, bc, wlc, blc, out, B);
}